// Round 10
// baseline (29.529 us; speedup 1.0000x reference)
//
#include <hip/hip_runtime.h>

// UserMerger — algebraic collapse:
//   triu(MASK_VAL, k=0) masks the diagonal, so diag(softmax)==0 for rows m>=1
//   (exp underflow). Row 0 is fully masked; in fp32, Q_K + (-2^32) rounds every
//   entry to exactly -2^32, so the row softmax is uniform and diag[b,0] ==
//   1/1024 exactly.
//   => out[b,0,d] = sum_m user[b,m,d] / 1024 ; out[b,l>0,:] = 0.
//   W1,b1,W2,b2,hyper_embedding are dead inputs.
//
// R9: single fused dispatch + 64B memset. reset() re-poisons 268MB between
// replays (> 256MB L3) so all residency plays are dead; the lever is dispatch
// count (≈4µs each). Last-arriver finalize: publish partial via relaxed sc1
// stores (no cache maintenance), vmcnt(0) drain, one counted atomicAdd; the
// block seeing old==63 knows all 64 publishes are acked at the coherence
// point -> folds and writes row 0. Spin-free (no hang mode), fence-free
// (no buffer_wbl2 storms), deterministic (fixed fold order; counters zeroed
// by memset every call, so correctness-call and replays are identical).

namespace {

typedef float f32x4 __attribute__((ext_vector_type(4)));
typedef float f32x2 __attribute__((ext_vector_type(2)));

constexpr int B   = 16;
constexpr int L   = 1024;
constexpr int D   = 512;
constexpr int RPB = 16;              // rows per block
constexpr int GPB = L / RPB;         // 64 blocks per batch

__global__ __launch_bounds__(256)
void fused_kernel(const float* __restrict__ user,
                  float* __restrict__ out,
                  unsigned long long* __restrict__ partial, // [B][GPB][D/2]
                  unsigned* __restrict__ counters)          // [B], pre-zeroed
{
    const int tid = threadIdx.x;
    const int bid = (int)blockIdx.x;
    const int b   = bid >> 6;            // batch
    const int r   = bid & (GPB - 1);     // row-group of 16 rows
    const int d4  = tid & 127;           // f32x4 column index
    const int rh  = tid >> 7;            // row-half 0/1

    const f32x4* src = reinterpret_cast<const f32x4*>(
        user + (size_t)(b * L + r * RPB) * D);

    // Column-partial over this block's 16 rows (8 rows per half).
    f32x4 acc = (f32x4)(0.f);
#pragma unroll
    for (int i = 0; i < 8; ++i)
        acc += __builtin_nontemporal_load(
            src + (size_t)(2 * i + rh) * (D / 4) + d4);

    __shared__ f32x4 sh[D / 4];
    __shared__ float sp[D];
    if (rh == 1) sh[d4] = acc;
    __syncthreads();
    if (rh == 0) {
        f32x4 t = acc + sh[d4];
        sp[4 * d4 + 0] = t.x; sp[4 * d4 + 1] = t.y;
        sp[4 * d4 + 2] = t.z; sp[4 * d4 + 3] = t.w;
    }
    __syncthreads();

    // Publish block partial: 256 threads × one u64 (cols 2t, 2t+1), sc1.
    f32x2 my = { sp[2 * tid], sp[2 * tid + 1] };
    __hip_atomic_store(partial + (size_t)(b * GPB + r) * (D / 2) + tid,
                       __builtin_bit_cast(unsigned long long, my),
                       __ATOMIC_RELAXED, __HIP_MEMORY_SCOPE_AGENT);
    asm volatile("s_waitcnt vmcnt(0)" ::: "memory");  // publish acked @ L3
    __syncthreads();        // every wave drained before the arrival bump

    __shared__ unsigned sold;
    if (tid == 0)
        sold = __hip_atomic_fetch_add(&counters[b], 1u,
                                      __ATOMIC_RELAXED,
                                      __HIP_MEMORY_SCOPE_AGENT);
    __syncthreads();
    const bool last = (sold == (unsigned)(GPB - 1));

    f32x4* dst = reinterpret_cast<f32x4*>(
        out + (size_t)(b * L + r * RPB) * D);
    const f32x4 z = (f32x4)(0.f);

    if (last) {
        // All 64 publishes for batch b are globally visible. Fold (fixed
        // order -> bit-deterministic) and write row 0. Critical path first.
        const unsigned long long* p = partial + (size_t)b * GPB * (D / 2) + tid;
        f32x2 a = (f32x2)(0.f);
#pragma unroll
        for (int s = 0; s < GPB; ++s) {
            unsigned long long u =
                __hip_atomic_load(p + (size_t)s * (D / 2),
                                  __ATOMIC_RELAXED, __HIP_MEMORY_SCOPE_AGENT);
            a += __builtin_bit_cast(f32x2, u);
        }
        a *= (1.0f / 1024.0f);           // diag of softmax == uniform 1/L
        reinterpret_cast<f32x2*>(out + (size_t)b * L * D)[tid] = a;
    }

    // Bulk zero of own 16 rows; block r==0 skips row 0 (finalizer owns it).
    const int first = (r == 0) ? (D / 4) : 0;
#pragma unroll
    for (int it = 0; it < 8; ++it) {
        const int idx = it * 256 + tid;
        if (idx >= first)
            __builtin_nontemporal_store(z, dst + idx);
    }
}

// Fallback (workspace unexpectedly tiny): memset + direct reduce.
__global__ void direct_row0_kernel(const float* __restrict__ user,
                                   float* __restrict__ out) {
    const int b  = blockIdx.x;
    const int d4 = threadIdx.x;
    const f32x4* src = reinterpret_cast<const f32x4*>(
        user + (size_t)b * L * D) + d4;
    f32x4 acc = (f32x4)(0.f);
    for (int m = 0; m < L; ++m)
        acc += src[(size_t)m * (D / 4)];
    acc *= (1.0f / 1024.0f);
    reinterpret_cast<f32x4*>(out + (size_t)b * L * D)[d4] = acc;
}

} // namespace

extern "C" void kernel_launch(void* const* d_in, const int* in_sizes, int n_in,
                              void* d_out, int out_size, void* d_ws, size_t ws_size,
                              hipStream_t stream) {
    const float* user = (const float*)d_in[0];   // [B, L, D] fp32
    float* out = (float*)d_out;                  // [B, L, D] fp32

    const size_t partial_bytes =
        (size_t)B * GPB * (D / 2) * sizeof(unsigned long long); // 2 MiB
    const size_t counter_bytes = (size_t)B * sizeof(unsigned);  // 64 B
    if (ws_size >= partial_bytes + counter_bytes) {
        unsigned long long* partial = (unsigned long long*)d_ws;
        unsigned* counters = (unsigned*)((char*)d_ws + partial_bytes);
        (void)hipMemsetAsync(counters, 0, counter_bytes, stream);
        fused_kernel<<<B * GPB, 256, 0, stream>>>(user, out, partial, counters);
    } else {
        (void)hipMemsetAsync(d_out, 0, (size_t)out_size * sizeof(float), stream);
        direct_row0_kernel<<<B, D / 4, 0, stream>>>(user, out);
    }
}

// Round 11
// 28.226 us; speedup vs baseline: 1.0462x; 1.0462x over previous
//
#include <hip/hip_runtime.h>

// UserMerger — algebraic collapse:
//   triu(MASK_VAL, k=0) masks the diagonal, so diag(softmax)==0 for rows m>=1
//   (exp underflow). Row 0 is fully masked; in fp32, Q_K + (-2^32) rounds every
//   entry to exactly -2^32, so the row softmax is uniform and diag[b,0] ==
//   1/1024 exactly.
//   => out[b,0,d] = sum_m user[b,m,d] / 1024 ; out[b,l>0,:] = 0.
//   W1,b1,W2,b2,hyper_embedding are dead inputs.
//
// R10: single fused dispatch + 32KB ws memset. R9 proved the last-arriver
// sync (vmcnt(0) drain -> counter bump) correct but its 2MB sc1 publish +
// 256KB/batch uncached fold tail cost ~10µs. R10 shrinks communicated state
// 64x: blocks unsafeAtomicAdd their scaled partials into a 32KB accumulator
// (native f32 atomics execute at the coherence point, fire-and-forget); the
// last arriver per batch reads 512 floats and writes row 0 (only writer of
// row 0 -> no pre-zeroing of out needed). Bulk zero of rows 1..1023 via nt
// stores as in R3. Spin-free, fence-free. fp32 atomic order varies in low
// bits only (~1e-6 << 2.4e-3 threshold).

namespace {

typedef float f32x4 __attribute__((ext_vector_type(4)));
typedef float f32x2 __attribute__((ext_vector_type(2)));

constexpr int B   = 16;
constexpr int L   = 1024;
constexpr int D   = 512;
constexpr int RPB = 16;              // rows per block
constexpr int GPB = L / RPB;         // 64 blocks per batch

__global__ __launch_bounds__(256)
void fused_kernel(const float* __restrict__ user,
                  float* __restrict__ out,
                  float* __restrict__ wsacc,       // [B][D], pre-zeroed
                  unsigned* __restrict__ counters) // [B],    pre-zeroed
{
    const int tid = threadIdx.x;
    const int bid = (int)blockIdx.x;
    const int b   = bid >> 6;            // batch
    const int r   = bid & (GPB - 1);     // row-group of 16 rows
    const int d4  = tid & 127;           // f32x4 column index
    const int rh  = tid >> 7;            // row-half 0/1

    const f32x4* src = reinterpret_cast<const f32x4*>(
        user + (size_t)(b * L + r * RPB) * D);

    // Column-partial over this block's 16 rows (8 rows per half).
    f32x4 acc = (f32x4)(0.f);
#pragma unroll
    for (int i = 0; i < 8; ++i)
        acc += __builtin_nontemporal_load(
            src + (size_t)(2 * i + rh) * (D / 4) + d4);

    __shared__ f32x4 sh[D / 4];
    __shared__ float sp[D];
    if (rh == 1) sh[d4] = acc;
    __syncthreads();
    if (rh == 0) {
        f32x4 t = acc + sh[d4];
        sp[4 * d4 + 0] = t.x; sp[4 * d4 + 1] = t.y;
        sp[4 * d4 + 2] = t.z; sp[4 * d4 + 3] = t.w;
    }
    __syncthreads();

    // Accumulate scaled partial into the 32KB ws accumulator.
    // 2 atomics/thread -> 512 per block, 64-way contention per address.
    const float s = 1.0f / 1024.0f;      // diag of softmax == uniform 1/L
    unsafeAtomicAdd(&wsacc[b * D + 2 * tid + 0], sp[2 * tid + 0] * s);
    unsafeAtomicAdd(&wsacc[b * D + 2 * tid + 1], sp[2 * tid + 1] * s);
    asm volatile("s_waitcnt vmcnt(0)" ::: "memory");  // adds acked @ L2/L3
    __syncthreads();        // every wave drained before the arrival bump

    __shared__ unsigned sold;
    if (tid == 0)
        sold = atomicAdd(&counters[b], 1u);   // device-scope (m20)
    __syncthreads();
    const bool last = (sold == (unsigned)(GPB - 1));

    f32x4* dst = reinterpret_cast<f32x4*>(
        out + (size_t)(b * L + r * RPB) * D);
    const f32x4 z = (f32x4)(0.f);

    if (last) {
        // All 64 blocks' adds are complete at the coherence point.
        // Read 512 floats (2/thread) and write row 0 — the only writer.
        unsigned long long u = __hip_atomic_load(
            reinterpret_cast<const unsigned long long*>(wsacc + b * D) + tid,
            __ATOMIC_RELAXED, __HIP_MEMORY_SCOPE_AGENT);
        reinterpret_cast<f32x2*>(out + (size_t)b * L * D)[tid] =
            __builtin_bit_cast(f32x2, u);
    }

    // Bulk zero of own 16 rows; block r==0 skips row 0 (finalizer owns it).
    const int first = (r == 0) ? (D / 4) : 0;
#pragma unroll
    for (int it = 0; it < 8; ++it) {
        const int idx = it * 256 + tid;
        if (idx >= first)
            __builtin_nontemporal_store(z, dst + idx);
    }
}

// Fallback (workspace unexpectedly tiny): memset + direct reduce.
__global__ void direct_row0_kernel(const float* __restrict__ user,
                                   float* __restrict__ out) {
    const int b  = blockIdx.x;
    const int d4 = threadIdx.x;
    const f32x4* src = reinterpret_cast<const f32x4*>(
        user + (size_t)b * L * D) + d4;
    f32x4 acc = (f32x4)(0.f);
    for (int m = 0; m < L; ++m)
        acc += src[(size_t)m * (D / 4)];
    acc *= (1.0f / 1024.0f);
    reinterpret_cast<f32x4*>(out + (size_t)b * L * D)[d4] = acc;
}

} // namespace

extern "C" void kernel_launch(void* const* d_in, const int* in_sizes, int n_in,
                              void* d_out, int out_size, void* d_ws, size_t ws_size,
                              hipStream_t stream) {
    const float* user = (const float*)d_in[0];   // [B, L, D] fp32
    float* out = (float*)d_out;                  // [B, L, D] fp32

    const size_t acc_bytes     = (size_t)B * D * sizeof(float);    // 32 KiB
    const size_t counter_bytes = (size_t)B * sizeof(unsigned);     // 64 B
    if (ws_size >= acc_bytes + counter_bytes) {
        float* wsacc = (float*)d_ws;
        unsigned* counters = (unsigned*)((char*)d_ws + acc_bytes);
        (void)hipMemsetAsync(d_ws, 0, acc_bytes + counter_bytes, stream);
        fused_kernel<<<B * GPB, 256, 0, stream>>>(user, out, wsacc, counters);
    } else {
        (void)hipMemsetAsync(d_out, 0, (size_t)out_size * sizeof(float), stream);
        direct_row0_kernel<<<B, D / 4, 0, stream>>>(user, out);
    }
}

// Round 12
// 18.681 us; speedup vs baseline: 1.5807x; 1.5109x over previous
//
#include <hip/hip_runtime.h>

// UserMerger — algebraic collapse:
//   triu(MASK_VAL, k=0) masks the diagonal, so diag(softmax)==0 for rows m>=1
//   (exp underflow). Row 0 is fully masked; in fp32, Q_K + (-2^32) rounds every
//   entry to exactly -2^32, so the row softmax is uniform and diag[b,0] ==
//   1/1024 exactly.
//   => out[b,0,d] = sum_m user[b,m,d] / 1024 ; out[b,l>0,:] = 0.
//   W1,b1,W2,b2,hyper_embedding are dead inputs.
//
// R11: REVERT to the R3 configuration — the measured optimum (18.79µs):
//   A: pure-read partial sums, nt loads (512 blocks x 128 thr).
//   B: pure-write zero + per-batch fold of 32 partials, nt stores
//      (1024 blocks x 256 thr).
// Session measurements: 3 dispatches = 22.3; every single-dispatch sync
// variant (sc1 publish/spin/counter/contended atomics/fences) = 24-267µs,
// i.e. intra-kernel cross-XCD sync always costs more than the ~3.5µs
// dispatch boundary it replaces. Harness re-fills 256MiB (== L3 size)
// between replays, so cross-replay cache residency is impossible and the
// 67MB compulsory HBM traffic (~10µs) + 2 dispatch overheads is the floor.

namespace {

typedef float f32x4 __attribute__((ext_vector_type(4)));
typedef float f32x2 __attribute__((ext_vector_type(2)));

constexpr int B    = 16;
constexpr int L    = 1024;
constexpr int D    = 512;
constexpr int MG   = 32;        // m-groups per batch (A grid = B*MG = 512)
constexpr int MPG  = L / MG;    // 32 rows per group
constexpr int TPBA = D / 4;     // 128 threads: one f32x4 lane per 4 d's

// Kernel A: partial[b][g][d] = sum_{m in group g} user[b][m][d]
__global__ __launch_bounds__(TPBA)
void partial_sum_kernel(const float* __restrict__ user,
                        float* __restrict__ partial) {
    const int blk = blockIdx.x;          // b * MG + g
    const int b   = blk >> 5;
    const int g   = blk & (MG - 1);
    const int d4  = threadIdx.x;         // 0..127
    const f32x4* src = reinterpret_cast<const f32x4*>(
        user + (size_t)(b * L + g * MPG) * D) + d4;
    f32x4 acc = (f32x4)(0.f);
#pragma unroll 8
    for (int m = 0; m < MPG; ++m)
        acc += __builtin_nontemporal_load(src + (size_t)m * (D / 4));
    reinterpret_cast<f32x4*>(partial + (size_t)(b * MG + g) * D)[d4] = acc;
}

// Kernel B: zero whole output; blocks owning rows 0..15 of a batch also
// reduce that batch's partials into row 0.
// Grid: B * 64 blocks, 256 threads. Each block covers 16 rows (2048 f32x4).
__global__ __launch_bounds__(256)
void zero_and_finalize_kernel(const float* __restrict__ partial,
                              float* __restrict__ out) {
    const int tid = threadIdx.x;
    const int bid = blockIdx.x;
    const int b   = bid >> 6;            // batch
    const int r   = bid & 63;            // row-group of 16 rows
    f32x4* dst = reinterpret_cast<f32x4*>(out + (size_t)(b * L + r * 16) * D);
    const f32x4 z = (f32x4)(0.f);

    if (r != 0) {
#pragma unroll
        for (int it = 0; it < 8; ++it)
            __builtin_nontemporal_store(z, dst + it * 256 + tid);
        return;
    }

    // r == 0: zero rows 1..15 (f32x4 idx 128..2047)
#pragma unroll
    for (int it = 0; it < 8; ++it) {
        const int idx = it * 256 + tid;
        if (idx >= D / 4)
            __builtin_nontemporal_store(z, dst + idx);
    }

    // Reduce 32 partials for this batch -> row 0 (64 KB, L2/L3-resident).
    const int d4   = tid & (TPBA - 1);   // 0..127
    const int part = tid >> 7;           // 0..1
    const f32x4* p = reinterpret_cast<const f32x4*>(
        partial + (size_t)(b * MG + part * (MG / 2)) * D) + d4;
    f32x4 acc = z;
#pragma unroll
    for (int g = 0; g < MG / 2; ++g)
        acc += p[(size_t)g * (D / 4)];
    __shared__ f32x4 sdata[2][TPBA];
    sdata[part][d4] = acc;
    __syncthreads();
    if (part == 0) {
        f32x4 a0 = sdata[0][d4], a1 = sdata[1][d4];
        const float s = 1.0f / 1024.0f;  // diag of softmax == uniform 1/L
        f32x4 rres = (a0 + a1) * s;
        dst[d4] = rres;
    }
}

// Fallback (only if workspace is unexpectedly tiny): memset + direct reduce.
__global__ void direct_row0_kernel(const float* __restrict__ user,
                                   float* __restrict__ out) {
    const int b  = blockIdx.x;
    const int d4 = threadIdx.x;
    const f32x4* src = reinterpret_cast<const f32x4*>(
        user + (size_t)b * L * D) + d4;
    f32x4 acc = (f32x4)(0.f);
    for (int m = 0; m < L; ++m)
        acc += src[(size_t)m * (D / 4)];
    acc *= (1.0f / 1024.0f);
    reinterpret_cast<f32x4*>(out + (size_t)b * L * D)[d4] = acc;
}

} // namespace

extern "C" void kernel_launch(void* const* d_in, const int* in_sizes, int n_in,
                              void* d_out, int out_size, void* d_ws, size_t ws_size,
                              hipStream_t stream) {
    const float* user = (const float*)d_in[0];   // [B, L, D] fp32
    float* out = (float*)d_out;                  // [B, L, D] fp32

    const size_t partial_bytes = (size_t)B * MG * D * sizeof(float); // 1 MiB
    if (ws_size >= partial_bytes) {
        float* partial = (float*)d_ws;
        partial_sum_kernel<<<B * MG, TPBA, 0, stream>>>(user, partial);
        zero_and_finalize_kernel<<<B * 64, 256, 0, stream>>>(partial, out);
    } else {
        (void)hipMemsetAsync(d_out, 0, (size_t)out_size * sizeof(float), stream);
        direct_row0_kernel<<<B, D / 4, 0, stream>>>(user, out);
    }
}